// Round 6
// baseline (88.842 us; speedup 1.0000x reference)
//
#include <hip/hip_runtime.h>

#define NN 512
#define TT 8
#define DD 64

// ---------------------------------------------------------------------------
// Kernel 1: projection.
//   L[t][n][h] = sum_d x[n][t][d] * W1[d][h]
//   R[t][n][h] = sum_d x[n][t][d] * W1[64+d][h] + b1[h]   (b1 folded into R)
// 512 blocks x 256 thr. Weight column in VGPRs (coalesced 256B/wave loads,
// W1 L2-resident); x reads wave-uniform broadcasts. Pure VALU inner loop.
// ---------------------------------------------------------------------------
__global__ __launch_bounds__(256) void k1_proj(const float* __restrict__ x,
                                               const float* __restrict__ W1,
                                               const float* __restrict__ b1,
                                               float* __restrict__ L,
                                               float* __restrict__ R)
{
    int g    = blockIdx.x * 256 + threadIdx.x;   // 0..131071
    int c    = g & 127;
    int h    = c & 63;
    int half = c >> 6;            // 0 -> L, 1 -> R
    int pair = g >> 7;            // 0..1023
    int n    = pair >> 1;         // 0..511
    int t0   = (pair & 1) * 4;    // t-split for 2x wave count

    float wcol[DD];
    const float* wbase = W1 + (half << 6) * DD + h;
#pragma unroll
    for (int d = 0; d < DD; ++d) wcol[d] = wbase[d << 6];

    float bias = half ? b1[h] : 0.0f;
    float* outbase = half ? R : L;

#pragma unroll
    for (int tt = 0; tt < 4; ++tt) {
        int t = t0 + tt;
        const float4* xr = (const float4*)(x + n * (TT * DD) + t * DD);
        float acc = 0.0f;
#pragma unroll
        for (int d4 = 0; d4 < 16; ++d4) {
            float4 xv = xr[d4];
            acc = fmaf(xv.x, wcol[d4 * 4 + 0], acc);
            acc = fmaf(xv.y, wcol[d4 * 4 + 1], acc);
            acc = fmaf(xv.z, wcol[d4 * 4 + 2], acc);
            acc = fmaf(xv.w, wcol[d4 * 4 + 3], acc);
        }
        outbase[t * (NN * DD) + n * DD + h] = acc + bias;
    }
}

// ---------------------------------------------------------------------------
// Kernel 2 (v4): pairwise relation. 256 blocks x 512 threads (8 waves).
//   A[i][j] = sum_t wts[t] * relu( sum_d relu(L[t,i,d]+R[t,j,d]) * w2[d] + b2 )
// Discriminator vs v3: NO dynamic LDS. L i-panel (all 8 t) in 64.25KB STATIC
// shared (XOR-swizzled); R streamed directly from global (L2-resident, 2MB;
// 16x chip-wide re-read = ~16MB L2 traffic, negligible). LDS-pipe load halves
// vs v3 (512 ds_read_b128/CU); k2 should be VALU-bound (~5 us floor).
// Wave w owns t=w, full 32x32 tile, 8x8 lane grid, 4x4 outputs/lane.
// Partials reduced through LDS aliased over the dead L tiles.
// ---------------------------------------------------------------------------
__global__ __launch_bounds__(512) void k2_main(const float* __restrict__ L,
                                               const float* __restrict__ R,
                                               const float* __restrict__ W2,
                                               const float* __restrict__ b2,
                                               const float* __restrict__ a,
                                               float* __restrict__ A)
{
    __shared__ float Sf[16384 + 64];   // 64.25 KB static
    float* const w2s = Sf + 16384;

    const int tid = threadIdx.x;
    const int i0  = blockIdx.y << 5;
    const int j0  = blockIdx.x << 5;

    // ---- stage L i-panel, all 8 t: 4096 float4, 8 per thread
#pragma unroll
    for (int k = 0; k < 8; ++k) {
        int e   = tid + (k << 9);     // 0..4095
        int t   = e >> 9;
        int w   = e & 511;
        int row = w >> 4;
        int c4  = w & 15;
        float4 v = ((const float4*)(L + t * (NN * DD) + (i0 + row) * DD))[c4];
        *(float4*)(Sf + t * 2048 + (row << 6) + ((c4 ^ ((row >> 1) & 7)) << 2)) = v;
    }
    if (tid < 64) w2s[tid] = W2[tid];

    const int wv   = tid >> 6;        // wave id == t
    const int lane = tid & 63;
    const int tjx  = lane & 7;        // j block (4 cols)
    const int tiy  = lane >> 3;       // i block (4 rows)

    // softmax weight for this wave's t (registers, redundant per thread)
    float wt;
    {
        float av[8];
#pragma unroll
        for (int t = 0; t < 8; ++t) av[t] = a[t];
        float m = av[0];
#pragma unroll
        for (int t = 1; t < 8; ++t) m = fmaxf(m, av[t]);
        float ssum = 0.0f;
#pragma unroll
        for (int t = 0; t < 8; ++t) ssum += expf(av[t] - m);
        wt = expf(av[wv] - m) / ssum
           * (1.0f + 0.5f * expf(-0.1f * (float)(7 - wv)));
    }
    const float b2v = b2[0];

    __syncthreads();

    // ---- compute: wave wv does t=wv, 4x4 per lane; L from LDS, R from L2
    const float* LB = Sf + wv * 2048;
    int lbase[4], lsw[4];
    const float4* Rrow[4];
#pragma unroll
    for (int r = 0; r < 4; ++r) {
        int li = 4 * tiy + r;
        lbase[r] = li << 6;  lsw[r] = (li >> 1) & 7;
        Rrow[r] = (const float4*)(R + wv * (NN * DD) + (j0 + 4 * tjx + r) * DD);
    }

    float acc[4][4];
#pragma unroll
    for (int p = 0; p < 4; ++p)
#pragma unroll
        for (int q = 0; q < 4; ++q) acc[p][q] = 0.0f;

#pragma unroll 4
    for (int d4 = 0; d4 < 16; ++d4) {
        float4 rv[4];
#pragma unroll
        for (int r = 0; r < 4; ++r) rv[r] = Rrow[r][d4];        // L2 hits
        float4 lv[4];
#pragma unroll
        for (int r = 0; r < 4; ++r)
            lv[r] = *(const float4*)(LB + lbase[r] + ((d4 ^ lsw[r]) << 2));
        float4 w4 = *(const float4*)(w2s + (d4 << 2));
#pragma unroll
        for (int p = 0; p < 4; ++p) {
#pragma unroll
            for (int q = 0; q < 4; ++q) {
                float s = acc[p][q];
                s = fmaf(fmaxf(lv[p].x + rv[q].x, 0.f), w4.x, s);
                s = fmaf(fmaxf(lv[p].y + rv[q].y, 0.f), w4.y, s);
                s = fmaf(fmaxf(lv[p].z + rv[q].z, 0.f), w4.z, s);
                s = fmaf(fmaxf(lv[p].w + rv[q].w, 0.f), w4.w, s);
                acc[p][q] = s;
            }
        }
    }

    // ---- epilogue per wave: relu + weight, dump partial into LDS
    __syncthreads();                  // all L reads done; Sf[0..8191] dead
    float* const P = Sf;              // 8 x 1024 floats (32KB, aliases L)
#pragma unroll
    for (int p = 0; p < 4; ++p) {
        float4 v = make_float4(
            wt * fmaxf(acc[p][0] + b2v, 0.f),
            wt * fmaxf(acc[p][1] + b2v, 0.f),
            wt * fmaxf(acc[p][2] + b2v, 0.f),
            wt * fmaxf(acc[p][3] + b2v, 0.f));
        *(float4*)(P + (wv << 10) + ((4 * tiy + p) << 5) + (tjx << 2)) = v;
    }
    __syncthreads();

    // ---- cross-t reduce + store: 512 threads, 2 outputs each
#pragma unroll
    for (int e = tid; e < 1024; e += 512) {
        float s = 0.0f;
#pragma unroll
        for (int t = 0; t < 8; ++t) s += P[(t << 10) + e];
        A[(i0 + (e >> 5)) * NN + j0 + (e & 31)] = s;
    }
}

extern "C" void kernel_launch(void* const* d_in, const int* in_sizes, int n_in,
                              void* d_out, int out_size, void* d_ws, size_t ws_size,
                              hipStream_t stream) {
    const float* x  = (const float*)d_in[0];
    const float* W1 = (const float*)d_in[1];
    const float* b1 = (const float*)d_in[2];
    const float* W2 = (const float*)d_in[3];
    const float* b2 = (const float*)d_in[4];
    const float* a  = (const float*)d_in[5];
    float* A = (float*)d_out;

    float* L = (float*)d_ws;                 // 8*512*64 f32 = 1 MB
    float* R = L + NN * TT * DD;             // 1 MB

    k1_proj<<<512, 256, 0, stream>>>(x, W1, b1, L, R);
    k2_main<<<dim3(16, 16), 512, 0, stream>>>(L, R, W2, b2, a, A);
}